// Round 6
// baseline (418.278 us; speedup 1.0000x reference)
//
#include <hip/hip_runtime.h>
#include <math.h>

// FeatureWeightNet: grid_sample(bilinear,border) -> group correlation (G=8) ->
// MLP(8->16->8->1) with per-batch BN stats -> sigmoid.
// R13: structural fixes on top of R12 (245.3 us):
//  - k_stats1: 360 -> 1440 blocks, straight-line 4 px/thread (occupancy was
//    1.4 waves/SIMD -> latency-exposed). Same moment-matrix math.
//  - reduce1/reduce2 dispatches eliminated: last-finishing stats block does
//    the reduction (partials + __threadfence + atomic ticket). 7 -> 5
//    dispatches (~10 us bubble each).
//  - Tickets live in d_out[0..1]: zeroed by k_transpose (runs first),
//    clobbered by k_final's real output. They cannot live in ws: all ws
//    bytes before sB are live featB data until k_sample completes.
//  - stats2/final 4-px straight-line bodies (LICM-proof) unchanged from R12.

constexpr int   Bc  = 2;
constexpr int   Cc  = 64;
constexpr int   Hc  = 256;
constexpr int   Wc  = 320;
constexpr int   NBc = 9;
constexpr int   HWc = Hc * Wc;            // 81920
constexpr int   NPIX = Bc * HWc;          // 163840
constexpr int   NPT  = Bc * NBc * HWc;    // 1474560 (= out_size)
constexpr float EPSV = 1e-5f;

constexpr int NBLK_S = NPIX / 32;         // 5120 sample blocks
constexpr int NBT4   = NPT / 1024;        // 1440 blocks, 4 px/thread (stats1/2, final)

// workspace layout in float units (~44 MB)
constexpr size_t OFF_FEATB = 0;                               // NHWC bf16: NPIX*64 ushort
constexpr size_t OFF_SB    = OFF_FEATB + (size_t)NPIX * 32;   // s bf16: NPT*8 ushort
// scratch overlays featB (dead after k_sample):
constexpr size_t OFF_P1    = 0;                                // NBT4*64 floats (44 used)
constexpr size_t OFF_P2    = OFF_P1 + (size_t)NBT4 * 64;       // NBT4*16 floats
constexpr size_t OFF_PAR1  = OFF_P2 + (size_t)NBT4 * 16;       // 272 floats
constexpr size_t OFF_PAR2  = OFF_PAR1 + 272;                   // 33 floats

__device__ __forceinline__ unsigned short f2bf_rne(float v) {
  unsigned int u = __float_as_uint(v);
  unsigned int r = (u + 0x7fffu + ((u >> 16) & 1u)) >> 16;
  return (unsigned short)r;
}
__device__ __forceinline__ void unpack8(uint4 u, float f[8]) {
  f[0] = __uint_as_float(u.x << 16);
  f[1] = __uint_as_float(u.x & 0xffff0000u);
  f[2] = __uint_as_float(u.y << 16);
  f[3] = __uint_as_float(u.y & 0xffff0000u);
  f[4] = __uint_as_float(u.z << 16);
  f[5] = __uint_as_float(u.z & 0xffff0000u);
  f[6] = __uint_as_float(u.w << 16);
  f[7] = __uint_as_float(u.w & 0xffff0000u);
}
__device__ __forceinline__ float dot8(const float s[8], float4 wa, float4 wb) {
  return s[0] * wa.x + s[1] * wa.y + s[2] * wa.z + s[3] * wa.w +
         s[4] * wb.x + s[5] * wb.y + s[6] * wb.z + s[7] * wb.w;
}

// ---------------------------------------------------------------------------
// K0: NCHW fp32 -> NHWC bf16 transpose; block 0 zeroes the 2 ticket slots
// that live at the head of the OUTPUT buffer (overwritten by k_final).
__global__ __launch_bounds__(256) void k_transpose(
    const float* __restrict__ feat, unsigned short* __restrict__ featB,
    unsigned int* __restrict__ tickets) {
  if (blockIdx.x == 0 && threadIdx.x < 2) tickets[threadIdx.x] = 0u;
  __shared__ float lds[64][65];
  const int tid  = threadIdx.x;
  const int b    = blockIdx.x / (HWc / 64);
  const int tile = blockIdx.x % (HWc / 64);
  const int hw0  = tile * 64;
  const int p    = tid & 63;
  const int ty   = tid >> 6;  // 0..3

  const float* src = feat + (size_t)b * Cc * HWc + hw0 + p;
#pragma unroll
  for (int c0 = 0; c0 < 64; c0 += 4) {
    lds[c0 + ty][p] = src[(size_t)(c0 + ty) * HWc];
  }
  __syncthreads();
  const int ch = tid & 63;
  unsigned short* dst = featB + ((size_t)b * HWc + hw0) * 64 + ch;
#pragma unroll
  for (int p0 = 0; p0 < 64; p0 += 4) {
    dst[(size_t)(p0 + ty) * 64] = f2bf_rne(lds[ch][p0 + ty]);
  }
}

// ---------------------------------------------------------------------------
// K1: grid sample + group correlation.  PURE gather kernel (proven 3.9 TB/s).
// UNCHANGED.
__global__ __launch_bounds__(256) void k_sample(
    const float* __restrict__ grid, const unsigned short* __restrict__ featB,
    unsigned short* __restrict__ sOut) {
  const int tid = threadIdx.x;
  const int cid = blockIdx.x * 32 + (tid >> 3);  // pixel id in [0, NPIX)
  const int j   = tid & 7;                       // group
  const int b   = cid / HWc;
  const int hw  = cid - b * HWc;
  const int h   = hw / Wc;
  const int w   = hw - h * Wc;

  const uint4* fbAll = (const uint4*)featB;
  const uint4 ur = fbAll[(size_t)cid * 8 + j];
  float r[8];
  unpack8(ur, r);

  const uint4* fb = fbAll + (size_t)b * HWc * 8;

#pragma unroll 3
  for (int n = 0; n < NBc; ++n) {
    const size_t gi = ((((size_t)b * NBc + n) * Hc + h) * Wc + w) * 2;
    const float2 g2 = *(const float2*)(grid + gi);
    float ix = ((g2.x + 1.f) * (float)Wc - 1.f) * 0.5f;
    float iy = ((g2.y + 1.f) * (float)Hc - 1.f) * 0.5f;
    ix = fminf(fmaxf(ix, 0.f), (float)(Wc - 1));
    iy = fminf(fmaxf(iy, 0.f), (float)(Hc - 1));
    const float x0f = floorf(ix), y0f = floorf(iy);
    const float fx = ix - x0f, fy = iy - y0f;
    const int x0 = (int)x0f, y0 = (int)y0f;
    const int x1 = min(x0 + 1, Wc - 1), y1 = min(y0 + 1, Hc - 1);
    const float w00 = (1.f - fx) * (1.f - fy);
    const float w01 = fx * (1.f - fy);
    const float w10 = (1.f - fx) * fy;
    const float w11 = fx * fy;

    const uint4 u00 = fb[(size_t)(y0 * Wc + x0) * 8 + j];
    const uint4 u01 = fb[(size_t)(y0 * Wc + x1) * 8 + j];
    const uint4 u10 = fb[(size_t)(y1 * Wc + x0) * 8 + j];
    const uint4 u11 = fb[(size_t)(y1 * Wc + x1) * 8 + j];
    float a[8], c[8], d[8], e[8];
    unpack8(u00, a);
    unpack8(u01, c);
    unpack8(u10, d);
    unpack8(u11, e);

    float s = 0.f;
#pragma unroll
    for (int k = 0; k < 8; ++k) {
      s += (w00 * a[k] + w01 * c[k] + w10 * d[k] + w11 * e[k]) * r[k];
    }
    s *= 0.125f;  // mean over C/G = 8

    const size_t pt = ((size_t)b * NBc + n) * HWc + hw;
    sOut[pt * 8 + j] = f2bf_rne(s);
  }
}

// ---------------------------------------------------------------------------
// K2: stats1 — straight-line 4 px/thread moment matrix of s
// (acc[0..7]=sum s_j; acc[8+tri(j,k)]=sum s_j s_k).  Block partials ->
// part1[b][64]; last block (ticket) reduces -> bn1 -> folded params par1:
// par1[0..127]=w0p (a1-folded w0), [128..143]=c1v, [144..271]=w1t ([c][o]).
__global__ __launch_bounds__(256) void k_stats1(
    const unsigned short* __restrict__ sB, const float* __restrict__ w0,
    const float* __restrict__ g0, const float* __restrict__ b0,
    const float* __restrict__ w1, float* __restrict__ part1,
    float* __restrict__ par1, unsigned int* __restrict__ tickets) {
  const int tid = threadIdx.x;
  float acc[44];
#pragma unroll
  for (int i = 0; i < 44; ++i) acc[i] = 0.f;

  const uint4* src = (const uint4*)sB + (size_t)blockIdx.x * 1024 + tid;
#pragma unroll
  for (int i = 0; i < 4; ++i) {
    float s[8];
    unpack8(src[i * 256], s);
#pragma unroll
    for (int j = 0; j < 8; ++j) acc[j] += s[j];
#pragma unroll
    for (int j = 0; j < 8; ++j) {
#pragma unroll
      for (int k = 0; k <= j; ++k) {
        acc[8 + j * (j + 1) / 2 + k] += s[j] * s[k];
      }
    }
  }
  __shared__ float red[4 * 44];
  __shared__ int lastFlag;
  const int wid = tid >> 6;
#pragma unroll
  for (int i = 0; i < 44; ++i) {
    float v = acc[i];
#pragma unroll
    for (int off = 32; off; off >>= 1) v += __shfl_xor(v, off);
    if ((tid & 63) == 0) red[wid * 44 + i] = v;
  }
  __syncthreads();
  if (tid < 44) {
    part1[blockIdx.x * 64 + tid] =
        red[tid] + red[44 + tid] + red[88 + tid] + red[132 + tid];
  }
  // ---- ticket: last block reduces part1 -> par1 ----
  __threadfence();
  __syncthreads();
  if (tid == 0) {
    const unsigned int old = atomicAdd(&tickets[0], 1u);
    lastFlag = (old == (unsigned int)(NBT4 - 1));
  }
  __syncthreads();
  if (!lastFlag) return;
  __threadfence();

  __shared__ float red2[1024], totm[64], a1s[16];
  {  // float4 partial reads: 16 row-chunks x 16 col-quads
    const int cq = tid & 15, chk = tid >> 4;
    float4 a = make_float4(0.f, 0.f, 0.f, 0.f);
    for (int r = chk; r < NBT4; r += 16) {
      const float4 v = *(const float4*)(part1 + r * 64 + cq * 4);
      a.x += v.x; a.y += v.y; a.z += v.z; a.w += v.w;
    }
    red2[chk * 64 + cq * 4 + 0] = a.x;
    red2[chk * 64 + cq * 4 + 1] = a.y;
    red2[chk * 64 + cq * 4 + 2] = a.z;
    red2[chk * 64 + cq * 4 + 3] = a.w;
  }
  __syncthreads();
  if (tid < 64) {
    float v = 0.f;
#pragma unroll
    for (int k = 0; k < 16; ++k) v += red2[k * 64 + tid];
    totm[tid] = v;
  }
  __syncthreads();
  if (tid < 16) {
    float wr[8];
    float mean = 0.f, ey2 = 0.f;
#pragma unroll
    for (int j = 0; j < 8; ++j) {
      wr[j] = w0[tid * 8 + j];
      mean += wr[j] * totm[j];
    }
#pragma unroll
    for (int j = 0; j < 8; ++j) {
#pragma unroll
      for (int k = 0; k <= j; ++k) {
        const float v = wr[j] * wr[k] * totm[8 + j * (j + 1) / 2 + k];
        ey2 += (k == j) ? v : 2.f * v;
      }
    }
    const float invN = 1.f / (float)NPT;
    mean *= invN;
    ey2 *= invN;
    const float var = ey2 - mean * mean;
    const float a = g0[tid] * rsqrtf(var + EPSV);
    a1s[tid] = a;
    par1[128 + tid] = b0[tid] - mean * a;
  }
  __syncthreads();
  if (tid < 128) {
    par1[tid] = a1s[tid >> 3] * w0[tid];                 // w0p
    par1[144 + (tid & 15) * 8 + (tid >> 4)] = w1[tid];   // w1t
  }
}

// ---------------------------------------------------------------------------
// K3: stats2 — straight-line 4 px/thread (LICM-proof); z/z^2 partials;
// last block (ticket) reduces part2 -> bn2 -> par2[o*4+{0,1,2}]={a2,c2,ws},
// par2[32]=bs.
__global__ __launch_bounds__(256) void k_stats2(
    const unsigned short* __restrict__ sB, const float* __restrict__ par1,
    const float* __restrict__ g1, const float* __restrict__ b1,
    const float* __restrict__ wsW, const float* __restrict__ bs,
    float* __restrict__ part2, float* __restrict__ par2,
    unsigned int* __restrict__ tickets) {
  __shared__ float w0ps[128], c1vs[16], w1ts[128];
  __shared__ float red[64];
  __shared__ int lastFlag;
  const int tid = threadIdx.x;
  if (tid < 128) {
    w0ps[tid] = par1[tid];
    w1ts[tid] = par1[144 + tid];
  }
  if (tid >= 128 && tid < 144) c1vs[tid - 128] = par1[tid];
  __syncthreads();

  const uint4* src = (const uint4*)sB + (size_t)blockIdx.x * 1024 + tid;
  float s0[8], s1[8], s2[8], s3[8];
  unpack8(src[0], s0);
  unpack8(src[256], s1);
  unpack8(src[512], s2);
  unpack8(src[768], s3);

  float z0[8], z1[8], z2[8], z3[8];
#pragma unroll
  for (int o = 0; o < 8; ++o) { z0[o] = 0.f; z1[o] = 0.f; z2[o] = 0.f; z3[o] = 0.f; }
#pragma unroll
  for (int c = 0; c < 16; ++c) {
    const float4 wa = *(const float4*)(w0ps + c * 8);
    const float4 wb = *(const float4*)(w0ps + c * 8 + 4);
    const float cc = c1vs[c];
    const float4 ta = *(const float4*)(w1ts + c * 8);
    const float4 tb = *(const float4*)(w1ts + c * 8 + 4);
    const float xa = fmaxf(dot8(s0, wa, wb) + cc, 0.f);
    const float xb = fmaxf(dot8(s1, wa, wb) + cc, 0.f);
    const float xc = fmaxf(dot8(s2, wa, wb) + cc, 0.f);
    const float xd = fmaxf(dot8(s3, wa, wb) + cc, 0.f);
    z0[0] += ta.x * xa; z0[1] += ta.y * xa; z0[2] += ta.z * xa; z0[3] += ta.w * xa;
    z0[4] += tb.x * xa; z0[5] += tb.y * xa; z0[6] += tb.z * xa; z0[7] += tb.w * xa;
    z1[0] += ta.x * xb; z1[1] += ta.y * xb; z1[2] += ta.z * xb; z1[3] += ta.w * xb;
    z1[4] += tb.x * xb; z1[5] += tb.y * xb; z1[6] += tb.z * xb; z1[7] += tb.w * xb;
    z2[0] += ta.x * xc; z2[1] += ta.y * xc; z2[2] += ta.z * xc; z2[3] += ta.w * xc;
    z2[4] += tb.x * xc; z2[5] += tb.y * xc; z2[6] += tb.z * xc; z2[7] += tb.w * xc;
    z3[0] += ta.x * xd; z3[1] += ta.y * xd; z3[2] += ta.z * xd; z3[3] += ta.w * xd;
    z3[4] += tb.x * xd; z3[5] += tb.y * xd; z3[6] += tb.z * xd; z3[7] += tb.w * xd;
  }

  const int wid = tid >> 6;
#pragma unroll
  for (int o = 0; o < 8; ++o) {
    float v = (z0[o] + z1[o]) + (z2[o] + z3[o]);
    float v2 = (z0[o] * z0[o] + z1[o] * z1[o]) + (z2[o] * z2[o] + z3[o] * z3[o]);
#pragma unroll
    for (int off = 32; off; off >>= 1) {
      v += __shfl_xor(v, off);
      v2 += __shfl_xor(v2, off);
    }
    if ((tid & 63) == 0) {
      red[wid * 16 + o] = v;
      red[wid * 16 + 8 + o] = v2;
    }
  }
  __syncthreads();
  if (tid < 16) {
    part2[blockIdx.x * 16 + tid] =
        red[tid] + red[16 + tid] + red[32 + tid] + red[48 + tid];
  }
  // ---- ticket: last block reduces part2 -> par2 ----
  __threadfence();
  __syncthreads();
  if (tid == 0) {
    const unsigned int old = atomicAdd(&tickets[1], 1u);
    lastFlag = (old == (unsigned int)(NBT4 - 1));
  }
  __syncthreads();
  if (!lastFlag) return;
  __threadfence();

  __shared__ float red2[1024], totz[16];
  {  // float4 partial reads: 64 row-chunks x 4 col-quads
    const int cq = tid & 3, chk = tid >> 2;
    float4 a = make_float4(0.f, 0.f, 0.f, 0.f);
    for (int r = chk; r < NBT4; r += 64) {
      const float4 v = *(const float4*)(part2 + r * 16 + cq * 4);
      a.x += v.x; a.y += v.y; a.z += v.z; a.w += v.w;
    }
    red2[chk * 16 + cq * 4 + 0] = a.x;
    red2[chk * 16 + cq * 4 + 1] = a.y;
    red2[chk * 16 + cq * 4 + 2] = a.z;
    red2[chk * 16 + cq * 4 + 3] = a.w;
  }
  __syncthreads();
  if (tid < 16) {
    float v = 0.f;
#pragma unroll
    for (int k = 0; k < 64; ++k) v += red2[k * 16 + tid];
    totz[tid] = v;
  }
  __syncthreads();
  if (tid < 8) {
    const float invN = 1.f / (float)NPT;
    const float mean = totz[tid] * invN;
    const float var = totz[8 + tid] * invN - mean * mean;
    const float a = g1[tid] * rsqrtf(var + EPSV);
    par2[tid * 4 + 0] = a;
    par2[tid * 4 + 1] = b1[tid] - mean * a;
    par2[tid * 4 + 2] = wsW[tid];
    par2[tid * 4 + 3] = 0.f;
  }
  if (tid == 8) par2[32] = bs[0];
}

// ---------------------------------------------------------------------------
// K4: final — straight-line 4 px/thread, full MLP + sigmoid -> out.
// (Overwrites the ticket words at out[0..1] with real results.)
__global__ __launch_bounds__(256) void k_final(
    const unsigned short* __restrict__ sB, const float* __restrict__ par1,
    const float* __restrict__ par2, float* __restrict__ out) {
  __shared__ float w0ps[128], c1vs[16], w1ts[128], w2s[33];
  const int tid = threadIdx.x;
  if (tid < 128) {
    w0ps[tid] = par1[tid];
    w1ts[tid] = par1[144 + tid];
  }
  if (tid >= 128 && tid < 144) c1vs[tid - 128] = par1[tid];
  if (tid >= 160 && tid < 193) w2s[tid - 160] = par2[tid - 160];
  __syncthreads();

  const uint4* src = (const uint4*)sB + (size_t)blockIdx.x * 1024 + tid;
  float s0[8], s1[8], s2[8], s3[8];
  unpack8(src[0], s0);
  unpack8(src[256], s1);
  unpack8(src[512], s2);
  unpack8(src[768], s3);

  float z0[8], z1[8], z2[8], z3[8];
#pragma unroll
  for (int o = 0; o < 8; ++o) { z0[o] = 0.f; z1[o] = 0.f; z2[o] = 0.f; z3[o] = 0.f; }
#pragma unroll
  for (int c = 0; c < 16; ++c) {
    const float4 wa = *(const float4*)(w0ps + c * 8);
    const float4 wb = *(const float4*)(w0ps + c * 8 + 4);
    const float cc = c1vs[c];
    const float4 ta = *(const float4*)(w1ts + c * 8);
    const float4 tb = *(const float4*)(w1ts + c * 8 + 4);
    const float xa = fmaxf(dot8(s0, wa, wb) + cc, 0.f);
    const float xb = fmaxf(dot8(s1, wa, wb) + cc, 0.f);
    const float xc = fmaxf(dot8(s2, wa, wb) + cc, 0.f);
    const float xd = fmaxf(dot8(s3, wa, wb) + cc, 0.f);
    z0[0] += ta.x * xa; z0[1] += ta.y * xa; z0[2] += ta.z * xa; z0[3] += ta.w * xa;
    z0[4] += tb.x * xa; z0[5] += tb.y * xa; z0[6] += tb.z * xa; z0[7] += tb.w * xa;
    z1[0] += ta.x * xb; z1[1] += ta.y * xb; z1[2] += ta.z * xb; z1[3] += ta.w * xb;
    z1[4] += tb.x * xb; z1[5] += tb.y * xb; z1[6] += tb.z * xb; z1[7] += tb.w * xb;
    z2[0] += ta.x * xc; z2[1] += ta.y * xc; z2[2] += ta.z * xc; z2[3] += ta.w * xc;
    z2[4] += tb.x * xc; z2[5] += tb.y * xc; z2[6] += tb.z * xc; z2[7] += tb.w * xc;
    z3[0] += ta.x * xd; z3[1] += ta.y * xd; z3[2] += ta.z * xd; z3[3] += ta.w * xd;
    z3[4] += tb.x * xd; z3[5] += tb.y * xd; z3[6] += tb.z * xd; z3[7] += tb.w * xd;
  }

  const float bsr = w2s[32];
  float r0 = bsr, r1 = bsr, r2 = bsr, r3 = bsr;
#pragma unroll
  for (int o = 0; o < 8; ++o) {
    const float4 pr = *(const float4*)(w2s + o * 4);
    r0 += pr.z * fmaxf(fmaf(pr.x, z0[o], pr.y), 0.f);
    r1 += pr.z * fmaxf(fmaf(pr.x, z1[o], pr.y), 0.f);
    r2 += pr.z * fmaxf(fmaf(pr.x, z2[o], pr.y), 0.f);
    r3 += pr.z * fmaxf(fmaf(pr.x, z3[o], pr.y), 0.f);
  }
  float* op = out + (size_t)blockIdx.x * 1024 + tid;
  op[0]   = 1.f / (1.f + __expf(-r0));
  op[256] = 1.f / (1.f + __expf(-r1));
  op[512] = 1.f / (1.f + __expf(-r2));
  op[768] = 1.f / (1.f + __expf(-r3));
}

// ---------------------------------------------------------------------------
extern "C" void kernel_launch(void* const* d_in, const int* in_sizes, int n_in,
                              void* d_out, int out_size, void* d_ws,
                              size_t ws_size, hipStream_t stream) {
  const float* feat = (const float*)d_in[0];  // [2,64,256,320]
  const float* grid = (const float*)d_in[1];  // [2,2304,320,2]
  const float* w0 = (const float*)d_in[2];    // [16,8]
  const float* g0 = (const float*)d_in[3];
  const float* b0 = (const float*)d_in[4];
  const float* w1 = (const float*)d_in[5];    // [8,16]
  const float* g1 = (const float*)d_in[6];
  const float* b1 = (const float*)d_in[7];
  const float* wsW = (const float*)d_in[8];   // [1,8]
  const float* bs = (const float*)d_in[9];    // [1]
  float* out = (float*)d_out;

  float* wsf = (float*)d_ws;  // ~45 MB
  unsigned short* featB = (unsigned short*)(wsf + OFF_FEATB);
  unsigned short* sB    = (unsigned short*)(wsf + OFF_SB);
  float* part1 = wsf + OFF_P1;   // overlays featB (dead after k_sample)
  float* part2 = wsf + OFF_P2;
  float* par1  = wsf + OFF_PAR1;
  float* par2  = wsf + OFF_PAR2;
  unsigned int* tickets = (unsigned int*)out;  // out[0..1]; k_final overwrites

  k_transpose<<<Bc * (HWc / 64), 256, 0, stream>>>(feat, featB, tickets);
  k_sample<<<NBLK_S, 256, 0, stream>>>(grid, featB, sB);
  k_stats1<<<NBT4, 256, 0, stream>>>(sB, w0, g0, b0, w1, part1, par1, tickets);
  k_stats2<<<NBT4, 256, 0, stream>>>(sB, par1, g1, b1, wsW, bs, part2, par2,
                                     tickets);
  k_final<<<NBT4, 256, 0, stream>>>(sB, par1, par2, out);
}

// Round 7
// 268.132 us; speedup vs baseline: 1.5600x; 1.5600x over previous
//
#include <hip/hip_runtime.h>
#include <math.h>

// FeatureWeightNet: grid_sample(bilinear,border) -> group correlation (G=8) ->
// MLP(8->16->8->1) with per-batch BN stats -> sigmoid.
// R14 = R12 (245.3us, best) + the one proven piece of R13:
//  - k_stats1: 1440 blocks, straight-line 4 px/thread (R12 had 360 blocks x
//    16-iter grid-stride = 1.4 blk/CU latency-exposed). NO ticket/fence —
//    R13 proved device-scope __threadfence in every block costs ~100us more
//    than a dedicated 5us reduce dispatch on 8 non-coherent XCDs.
//  - reduce1/reduce2 single-block dispatches restored (bounds -> 1440 rows).
//  - transpose / sample / stats2 / final byte-identical to R12
//    (straight-line = LICM-proof: no loop around LDS weight reads).
// 7 dispatches, no atomics, no fences.

constexpr int   Bc  = 2;
constexpr int   Cc  = 64;
constexpr int   Hc  = 256;
constexpr int   Wc  = 320;
constexpr int   NBc = 9;
constexpr int   HWc = Hc * Wc;            // 81920
constexpr int   NPIX = Bc * HWc;          // 163840
constexpr int   NPT  = Bc * NBc * HWc;    // 1474560 (= out_size)
constexpr float EPSV = 1e-5f;

constexpr int NBLK_S = NPIX / 32;         // 5120 sample blocks
constexpr int NBT4   = NPT / 1024;        // 1440 blocks, 4 px/thread

// workspace layout in float units (~44 MB)
constexpr size_t OFF_FEATB = 0;                               // NHWC bf16: NPIX*64 ushort
constexpr size_t OFF_SB    = OFF_FEATB + (size_t)NPIX * 32;   // s bf16: NPT*8 ushort
// scratch overlays featB (dead after k_sample):
constexpr size_t OFF_P1    = 0;                                // NBT4*64 floats (44 used)
constexpr size_t OFF_P2    = OFF_P1 + (size_t)NBT4 * 64;       // NBT4*16 floats
constexpr size_t OFF_PAR1  = OFF_P2 + (size_t)NBT4 * 16;       // 272 floats
constexpr size_t OFF_PAR2  = OFF_PAR1 + 272;                   // 33 floats

__device__ __forceinline__ unsigned short f2bf_rne(float v) {
  unsigned int u = __float_as_uint(v);
  unsigned int r = (u + 0x7fffu + ((u >> 16) & 1u)) >> 16;
  return (unsigned short)r;
}
__device__ __forceinline__ void unpack8(uint4 u, float f[8]) {
  f[0] = __uint_as_float(u.x << 16);
  f[1] = __uint_as_float(u.x & 0xffff0000u);
  f[2] = __uint_as_float(u.y << 16);
  f[3] = __uint_as_float(u.y & 0xffff0000u);
  f[4] = __uint_as_float(u.z << 16);
  f[5] = __uint_as_float(u.z & 0xffff0000u);
  f[6] = __uint_as_float(u.w << 16);
  f[7] = __uint_as_float(u.w & 0xffff0000u);
}
__device__ __forceinline__ float dot8(const float s[8], float4 wa, float4 wb) {
  return s[0] * wa.x + s[1] * wa.y + s[2] * wa.z + s[3] * wa.w +
         s[4] * wb.x + s[5] * wb.y + s[6] * wb.z + s[7] * wb.w;
}

// ---------------------------------------------------------------------------
// K0: NCHW fp32 -> NHWC bf16 transpose.
__global__ __launch_bounds__(256) void k_transpose(
    const float* __restrict__ feat, unsigned short* __restrict__ featB) {
  __shared__ float lds[64][65];
  const int tid  = threadIdx.x;
  const int b    = blockIdx.x / (HWc / 64);
  const int tile = blockIdx.x % (HWc / 64);
  const int hw0  = tile * 64;
  const int p    = tid & 63;
  const int ty   = tid >> 6;  // 0..3

  const float* src = feat + (size_t)b * Cc * HWc + hw0 + p;
#pragma unroll
  for (int c0 = 0; c0 < 64; c0 += 4) {
    lds[c0 + ty][p] = src[(size_t)(c0 + ty) * HWc];
  }
  __syncthreads();
  const int ch = tid & 63;
  unsigned short* dst = featB + ((size_t)b * HWc + hw0) * 64 + ch;
#pragma unroll
  for (int p0 = 0; p0 < 64; p0 += 4) {
    dst[(size_t)(p0 + ty) * 64] = f2bf_rne(lds[ch][p0 + ty]);
  }
}

// ---------------------------------------------------------------------------
// K1: grid sample + group correlation.  PURE gather kernel (proven 3.9 TB/s).
// UNCHANGED.
__global__ __launch_bounds__(256) void k_sample(
    const float* __restrict__ grid, const unsigned short* __restrict__ featB,
    unsigned short* __restrict__ sOut) {
  const int tid = threadIdx.x;
  const int cid = blockIdx.x * 32 + (tid >> 3);  // pixel id in [0, NPIX)
  const int j   = tid & 7;                       // group
  const int b   = cid / HWc;
  const int hw  = cid - b * HWc;
  const int h   = hw / Wc;
  const int w   = hw - h * Wc;

  const uint4* fbAll = (const uint4*)featB;
  const uint4 ur = fbAll[(size_t)cid * 8 + j];
  float r[8];
  unpack8(ur, r);

  const uint4* fb = fbAll + (size_t)b * HWc * 8;

#pragma unroll 3
  for (int n = 0; n < NBc; ++n) {
    const size_t gi = ((((size_t)b * NBc + n) * Hc + h) * Wc + w) * 2;
    const float2 g2 = *(const float2*)(grid + gi);
    float ix = ((g2.x + 1.f) * (float)Wc - 1.f) * 0.5f;
    float iy = ((g2.y + 1.f) * (float)Hc - 1.f) * 0.5f;
    ix = fminf(fmaxf(ix, 0.f), (float)(Wc - 1));
    iy = fminf(fmaxf(iy, 0.f), (float)(Hc - 1));
    const float x0f = floorf(ix), y0f = floorf(iy);
    const float fx = ix - x0f, fy = iy - y0f;
    const int x0 = (int)x0f, y0 = (int)y0f;
    const int x1 = min(x0 + 1, Wc - 1), y1 = min(y0 + 1, Hc - 1);
    const float w00 = (1.f - fx) * (1.f - fy);
    const float w01 = fx * (1.f - fy);
    const float w10 = (1.f - fx) * fy;
    const float w11 = fx * fy;

    const uint4 u00 = fb[(size_t)(y0 * Wc + x0) * 8 + j];
    const uint4 u01 = fb[(size_t)(y0 * Wc + x1) * 8 + j];
    const uint4 u10 = fb[(size_t)(y1 * Wc + x0) * 8 + j];
    const uint4 u11 = fb[(size_t)(y1 * Wc + x1) * 8 + j];
    float a[8], c[8], d[8], e[8];
    unpack8(u00, a);
    unpack8(u01, c);
    unpack8(u10, d);
    unpack8(u11, e);

    float s = 0.f;
#pragma unroll
    for (int k = 0; k < 8; ++k) {
      s += (w00 * a[k] + w01 * c[k] + w10 * d[k] + w11 * e[k]) * r[k];
    }
    s *= 0.125f;  // mean over C/G = 8

    const size_t pt = ((size_t)b * NBc + n) * HWc + hw;
    sOut[pt * 8 + j] = f2bf_rne(s);
  }
}

// ---------------------------------------------------------------------------
// K2: stats1 — straight-line 4 px/thread moment matrix of s
// (acc[0..7]=sum s_j; acc[8+tri(j,k)]=sum s_j s_k).  Partials only; no
// ticket, no fence (R13 lesson: device-scope fences cost ~100us).
__global__ __launch_bounds__(256) void k_stats1(
    const unsigned short* __restrict__ sB, float* __restrict__ part1) {
  const int tid = threadIdx.x;
  float acc[44];
#pragma unroll
  for (int i = 0; i < 44; ++i) acc[i] = 0.f;

  const uint4* src = (const uint4*)sB + (size_t)blockIdx.x * 1024 + tid;
#pragma unroll
  for (int i = 0; i < 4; ++i) {
    float s[8];
    unpack8(src[i * 256], s);
#pragma unroll
    for (int j = 0; j < 8; ++j) acc[j] += s[j];
#pragma unroll
    for (int j = 0; j < 8; ++j) {
#pragma unroll
      for (int k = 0; k <= j; ++k) {
        acc[8 + j * (j + 1) / 2 + k] += s[j] * s[k];
      }
    }
  }
  __shared__ float red[4 * 44];
  const int wid = tid >> 6;
#pragma unroll
  for (int i = 0; i < 44; ++i) {
    float v = acc[i];
#pragma unroll
    for (int off = 32; off; off >>= 1) v += __shfl_xor(v, off);
    if ((tid & 63) == 0) red[wid * 44 + i] = v;
  }
  __syncthreads();
  if (tid < 44) {
    part1[blockIdx.x * 64 + tid] =
        red[tid] + red[44 + tid] + red[88 + tid] + red[132 + tid];
  }
}

// ---------------------------------------------------------------------------
// K2b: reduce1 (1 block) — part1 (1440 x 64) -> moments -> bn1; write folded
// params: par1[0..127]=w0p (a1-folded w0), [128..143]=c1v, [144..271]=w1t.
__global__ __launch_bounds__(256) void k_reduce1(
    const float* __restrict__ part1, const float* __restrict__ w0,
    const float* __restrict__ w1, const float* __restrict__ g0,
    const float* __restrict__ b0, float* __restrict__ par1) {
  __shared__ float red[1024], totm[64], a1s[16];
  const int tid = threadIdx.x;
  {  // float4 partial reads: 16 row-chunks x 16 col-quads, 90 iters each
    const int cq = tid & 15, chk = tid >> 4;
    float4 a = make_float4(0.f, 0.f, 0.f, 0.f);
    for (int r = chk; r < NBT4; r += 16) {
      const float4 v = *(const float4*)(part1 + r * 64 + cq * 4);
      a.x += v.x; a.y += v.y; a.z += v.z; a.w += v.w;
    }
    red[chk * 64 + cq * 4 + 0] = a.x;
    red[chk * 64 + cq * 4 + 1] = a.y;
    red[chk * 64 + cq * 4 + 2] = a.z;
    red[chk * 64 + cq * 4 + 3] = a.w;
  }
  __syncthreads();
  if (tid < 64) {
    float v = 0.f;
#pragma unroll
    for (int k = 0; k < 16; ++k) v += red[k * 64 + tid];
    totm[tid] = v;
  }
  __syncthreads();
  if (tid < 16) {
    float wr[8];
    float mean = 0.f, ey2 = 0.f;
#pragma unroll
    for (int j = 0; j < 8; ++j) {
      wr[j] = w0[tid * 8 + j];
      mean += wr[j] * totm[j];
    }
#pragma unroll
    for (int j = 0; j < 8; ++j) {
#pragma unroll
      for (int k = 0; k <= j; ++k) {
        const float v = wr[j] * wr[k] * totm[8 + j * (j + 1) / 2 + k];
        ey2 += (k == j) ? v : 2.f * v;
      }
    }
    const float invN = 1.f / (float)NPT;
    mean *= invN;
    ey2 *= invN;
    const float var = ey2 - mean * mean;
    const float a = g0[tid] * rsqrtf(var + EPSV);
    a1s[tid] = a;
    par1[128 + tid] = b0[tid] - mean * a;
  }
  __syncthreads();
  if (tid < 128) {
    par1[tid] = a1s[tid >> 3] * w0[tid];                 // w0p
    par1[144 + (tid & 15) * 8 + (tid >> 4)] = w1[tid];   // w1t
  }
}

// ---------------------------------------------------------------------------
// K3: stats2 — straight-line 4 px/thread (LICM-proof); z/z^2 partials.
__global__ __launch_bounds__(256) void k_stats2(
    const unsigned short* __restrict__ sB, const float* __restrict__ par1,
    float* __restrict__ part2) {
  __shared__ float w0ps[128], c1vs[16], w1ts[128];
  __shared__ float red[64];
  const int tid = threadIdx.x;
  if (tid < 128) {
    w0ps[tid] = par1[tid];
    w1ts[tid] = par1[144 + tid];
  }
  if (tid >= 128 && tid < 144) c1vs[tid - 128] = par1[tid];
  __syncthreads();

  const uint4* src = (const uint4*)sB + (size_t)blockIdx.x * 1024 + tid;
  float s0[8], s1[8], s2[8], s3[8];
  unpack8(src[0], s0);
  unpack8(src[256], s1);
  unpack8(src[512], s2);
  unpack8(src[768], s3);

  float z0[8], z1[8], z2[8], z3[8];
#pragma unroll
  for (int o = 0; o < 8; ++o) { z0[o] = 0.f; z1[o] = 0.f; z2[o] = 0.f; z3[o] = 0.f; }
#pragma unroll
  for (int c = 0; c < 16; ++c) {
    const float4 wa = *(const float4*)(w0ps + c * 8);
    const float4 wb = *(const float4*)(w0ps + c * 8 + 4);
    const float cc = c1vs[c];
    const float4 ta = *(const float4*)(w1ts + c * 8);
    const float4 tb = *(const float4*)(w1ts + c * 8 + 4);
    const float xa = fmaxf(dot8(s0, wa, wb) + cc, 0.f);
    const float xb = fmaxf(dot8(s1, wa, wb) + cc, 0.f);
    const float xc = fmaxf(dot8(s2, wa, wb) + cc, 0.f);
    const float xd = fmaxf(dot8(s3, wa, wb) + cc, 0.f);
    z0[0] += ta.x * xa; z0[1] += ta.y * xa; z0[2] += ta.z * xa; z0[3] += ta.w * xa;
    z0[4] += tb.x * xa; z0[5] += tb.y * xa; z0[6] += tb.z * xa; z0[7] += tb.w * xa;
    z1[0] += ta.x * xb; z1[1] += ta.y * xb; z1[2] += ta.z * xb; z1[3] += ta.w * xb;
    z1[4] += tb.x * xb; z1[5] += tb.y * xb; z1[6] += tb.z * xb; z1[7] += tb.w * xb;
    z2[0] += ta.x * xc; z2[1] += ta.y * xc; z2[2] += ta.z * xc; z2[3] += ta.w * xc;
    z2[4] += tb.x * xc; z2[5] += tb.y * xc; z2[6] += tb.z * xc; z2[7] += tb.w * xc;
    z3[0] += ta.x * xd; z3[1] += ta.y * xd; z3[2] += ta.z * xd; z3[3] += ta.w * xd;
    z3[4] += tb.x * xd; z3[5] += tb.y * xd; z3[6] += tb.z * xd; z3[7] += tb.w * xd;
  }

  const int wid = tid >> 6;
#pragma unroll
  for (int o = 0; o < 8; ++o) {
    float v = (z0[o] + z1[o]) + (z2[o] + z3[o]);
    float v2 = (z0[o] * z0[o] + z1[o] * z1[o]) + (z2[o] * z2[o] + z3[o] * z3[o]);
#pragma unroll
    for (int off = 32; off; off >>= 1) {
      v += __shfl_xor(v, off);
      v2 += __shfl_xor(v2, off);
    }
    if ((tid & 63) == 0) {
      red[wid * 16 + o] = v;
      red[wid * 16 + 8 + o] = v2;
    }
  }
  __syncthreads();
  if (tid < 16) {
    part2[blockIdx.x * 16 + tid] =
        red[tid] + red[16 + tid] + red[32 + tid] + red[48 + tid];
  }
}

// ---------------------------------------------------------------------------
// K3b: reduce2 (1 block) — part2 (1440 x 16) -> bn2; par2[o*4+{0,1,2}] =
// {a2,c2,ws}, par2[32] = bs.
__global__ __launch_bounds__(256) void k_reduce2(
    const float* __restrict__ part2, const float* __restrict__ g1,
    const float* __restrict__ b1, const float* __restrict__ wsW,
    const float* __restrict__ bs, float* __restrict__ par2) {
  __shared__ float red[1024], totz[16];
  const int tid = threadIdx.x;
  {  // float4 partial reads: 64 row-chunks x 4 col-quads, 23 iters each
    const int cq = tid & 3, chk = tid >> 2;
    float4 a = make_float4(0.f, 0.f, 0.f, 0.f);
    for (int r = chk; r < NBT4; r += 64) {
      const float4 v = *(const float4*)(part2 + r * 16 + cq * 4);
      a.x += v.x; a.y += v.y; a.z += v.z; a.w += v.w;
    }
    red[chk * 16 + cq * 4 + 0] = a.x;
    red[chk * 16 + cq * 4 + 1] = a.y;
    red[chk * 16 + cq * 4 + 2] = a.z;
    red[chk * 16 + cq * 4 + 3] = a.w;
  }
  __syncthreads();
  if (tid < 16) {
    float v = 0.f;
#pragma unroll
    for (int k = 0; k < 64; ++k) v += red[k * 16 + tid];
    totz[tid] = v;
  }
  __syncthreads();
  if (tid < 8) {
    const float invN = 1.f / (float)NPT;
    const float mean = totz[tid] * invN;
    const float var = totz[8 + tid] * invN - mean * mean;
    const float a = g1[tid] * rsqrtf(var + EPSV);
    par2[tid * 4 + 0] = a;
    par2[tid * 4 + 1] = b1[tid] - mean * a;
    par2[tid * 4 + 2] = wsW[tid];
    par2[tid * 4 + 3] = 0.f;
  }
  if (tid == 8) par2[32] = bs[0];
}

// ---------------------------------------------------------------------------
// K4: final — straight-line 4 px/thread, full MLP + sigmoid -> out.
__global__ __launch_bounds__(256) void k_final(
    const unsigned short* __restrict__ sB, const float* __restrict__ par1,
    const float* __restrict__ par2, float* __restrict__ out) {
  __shared__ float w0ps[128], c1vs[16], w1ts[128], w2s[33];
  const int tid = threadIdx.x;
  if (tid < 128) {
    w0ps[tid] = par1[tid];
    w1ts[tid] = par1[144 + tid];
  }
  if (tid >= 128 && tid < 144) c1vs[tid - 128] = par1[tid];
  if (tid >= 160 && tid < 193) w2s[tid - 160] = par2[tid - 160];
  __syncthreads();

  const uint4* src = (const uint4*)sB + (size_t)blockIdx.x * 1024 + tid;
  float s0[8], s1[8], s2[8], s3[8];
  unpack8(src[0], s0);
  unpack8(src[256], s1);
  unpack8(src[512], s2);
  unpack8(src[768], s3);

  float z0[8], z1[8], z2[8], z3[8];
#pragma unroll
  for (int o = 0; o < 8; ++o) { z0[o] = 0.f; z1[o] = 0.f; z2[o] = 0.f; z3[o] = 0.f; }
#pragma unroll
  for (int c = 0; c < 16; ++c) {
    const float4 wa = *(const float4*)(w0ps + c * 8);
    const float4 wb = *(const float4*)(w0ps + c * 8 + 4);
    const float cc = c1vs[c];
    const float4 ta = *(const float4*)(w1ts + c * 8);
    const float4 tb = *(const float4*)(w1ts + c * 8 + 4);
    const float xa = fmaxf(dot8(s0, wa, wb) + cc, 0.f);
    const float xb = fmaxf(dot8(s1, wa, wb) + cc, 0.f);
    const float xc = fmaxf(dot8(s2, wa, wb) + cc, 0.f);
    const float xd = fmaxf(dot8(s3, wa, wb) + cc, 0.f);
    z0[0] += ta.x * xa; z0[1] += ta.y * xa; z0[2] += ta.z * xa; z0[3] += ta.w * xa;
    z0[4] += tb.x * xa; z0[5] += tb.y * xa; z0[6] += tb.z * xa; z0[7] += tb.w * xa;
    z1[0] += ta.x * xb; z1[1] += ta.y * xb; z1[2] += ta.z * xb; z1[3] += ta.w * xb;
    z1[4] += tb.x * xb; z1[5] += tb.y * xb; z1[6] += tb.z * xb; z1[7] += tb.w * xb;
    z2[0] += ta.x * xc; z2[1] += ta.y * xc; z2[2] += ta.z * xc; z2[3] += ta.w * xc;
    z2[4] += tb.x * xc; z2[5] += tb.y * xc; z2[6] += tb.z * xc; z2[7] += tb.w * xc;
    z3[0] += ta.x * xd; z3[1] += ta.y * xd; z3[2] += ta.z * xd; z3[3] += ta.w * xd;
    z3[4] += tb.x * xd; z3[5] += tb.y * xd; z3[6] += tb.z * xd; z3[7] += tb.w * xd;
  }

  const float bsr = w2s[32];
  float r0 = bsr, r1 = bsr, r2 = bsr, r3 = bsr;
#pragma unroll
  for (int o = 0; o < 8; ++o) {
    const float4 pr = *(const float4*)(w2s + o * 4);
    r0 += pr.z * fmaxf(fmaf(pr.x, z0[o], pr.y), 0.f);
    r1 += pr.z * fmaxf(fmaf(pr.x, z1[o], pr.y), 0.f);
    r2 += pr.z * fmaxf(fmaf(pr.x, z2[o], pr.y), 0.f);
    r3 += pr.z * fmaxf(fmaf(pr.x, z3[o], pr.y), 0.f);
  }
  float* op = out + (size_t)blockIdx.x * 1024 + tid;
  op[0]   = 1.f / (1.f + __expf(-r0));
  op[256] = 1.f / (1.f + __expf(-r1));
  op[512] = 1.f / (1.f + __expf(-r2));
  op[768] = 1.f / (1.f + __expf(-r3));
}

// ---------------------------------------------------------------------------
extern "C" void kernel_launch(void* const* d_in, const int* in_sizes, int n_in,
                              void* d_out, int out_size, void* d_ws,
                              size_t ws_size, hipStream_t stream) {
  const float* feat = (const float*)d_in[0];  // [2,64,256,320]
  const float* grid = (const float*)d_in[1];  // [2,2304,320,2]
  const float* w0 = (const float*)d_in[2];    // [16,8]
  const float* g0 = (const float*)d_in[3];
  const float* b0 = (const float*)d_in[4];
  const float* w1 = (const float*)d_in[5];    // [8,16]
  const float* g1 = (const float*)d_in[6];
  const float* b1 = (const float*)d_in[7];
  const float* wsW = (const float*)d_in[8];   // [1,8]
  const float* bs = (const float*)d_in[9];    // [1]
  float* out = (float*)d_out;

  float* wsf = (float*)d_ws;  // ~45 MB
  unsigned short* featB = (unsigned short*)(wsf + OFF_FEATB);
  unsigned short* sB    = (unsigned short*)(wsf + OFF_SB);
  float* part1 = wsf + OFF_P1;   // overlays featB (dead after k_sample)
  float* part2 = wsf + OFF_P2;
  float* par1  = wsf + OFF_PAR1;
  float* par2  = wsf + OFF_PAR2;

  k_transpose<<<Bc * (HWc / 64), 256, 0, stream>>>(feat, featB);
  k_sample<<<NBLK_S, 256, 0, stream>>>(grid, featB, sB);
  k_stats1<<<NBT4, 256, 0, stream>>>(sB, part1);
  k_reduce1<<<1, 256, 0, stream>>>(part1, w0, w1, g0, b0, par1);
  k_stats2<<<NBT4, 256, 0, stream>>>(sB, par1, part2);
  k_reduce2<<<1, 256, 0, stream>>>(part2, g1, b1, wsW, bs, par2);
  k_final<<<NBT4, 256, 0, stream>>>(sB, par1, par2, out);
}